// Round 2
// baseline (121.934 us; speedup 1.0000x reference)
//
#include <hip/hip_runtime.h>

#define BIG 1e20f

// Kernel A: per-(b,l) 8-tap softmax weights w[b,l,k] from delta_time.
// B*L = 32768 threads. Output to workspace: (B, L, 8) f32 = 1 MiB.
__global__ __launch_bounds__(256) void wtime_kernel(const float* __restrict__ dt,
                                                    float* __restrict__ w,
                                                    int B, int L) {
    int idx = blockIdx.x * 256 + threadIdx.x;
    int b = idx >> 12;           // L = 4096
    int l = idx & (L - 1);
    const float* dtb = dt + (size_t)b * L;
    float dtl = dtb[l];

    float v[8];
#pragma unroll
    for (int k = 0; k < 8; ++k) {
        // reference: where(l < k, BIG, dt[l-k]) - dt[l]; in fp32 BIG - dtl == BIG
        v[k] = (l < k) ? (BIG - dtl) : (dtb[l - k] - dtl);
    }
    float m = v[0];
#pragma unroll
    for (int k = 1; k < 8; ++k) m = fmaxf(m, v[k]);
    float s = 0.f;
#pragma unroll
    for (int k = 0; k < 8; ++k) { v[k] = __expf(v[k] - m); s += v[k]; }
    float inv = 1.f / s;

    float4 w0 = make_float4(v[0] * inv, v[1] * inv, v[2] * inv, v[3] * inv);
    float4 w1 = make_float4(v[4] * inv, v[5] * inv, v[6] * inv, v[7] * inv);
    float4* dst = reinterpret_cast<float4*>(w + (size_t)idx * 8);
    dst[0] = w0;
    dst[1] = w1;
}

// Kernel B: one block per (b,c) row. Each thread owns 16 contiguous l.
// t[l] = sum_k x[l-k] * w[b,l,k];  p[l] = sum_k x[l-k] * ker[k]
// G = [[t.t, t.p],[t.p, p.p]]; row-softmax; out = 0.5*(s00+s10)*t + 0.5*(s01+s11)*p
__global__ __launch_bounds__(256) void main_kernel(const float* __restrict__ x,
                                                   const float* __restrict__ w,
                                                   const float* __restrict__ ker,
                                                   float* __restrict__ out,
                                                   int C, int L) {
    const int bc  = blockIdx.x;       // b*C + c
    const int b   = bc >> 8;          // C = 256
    const int tid = threadIdx.x;

    const float* xrow = x + (size_t)bc * L;
    const float* wrow = w + (size_t)b * L * 8;
    float*       orow = out + (size_t)bc * L;

    float kk[8];
#pragma unroll
    for (int k = 0; k < 8; ++k) kk[k] = ker[k];

    const int l0 = tid * 16;

    // x window [l0-8, l0+16): 24 floats, 16B-aligned (l0-8 is a multiple of 8 floats - 32B).
    float xw[24];
    if (tid == 0) {
#pragma unroll
        for (int i = 0; i < 8; ++i) xw[i] = 0.f;   // x[-8..-1] -> masked to 0
    } else {
        float4 a0 = *reinterpret_cast<const float4*>(xrow + l0 - 8);
        float4 a1 = *reinterpret_cast<const float4*>(xrow + l0 - 4);
        xw[0] = a0.x; xw[1] = a0.y; xw[2] = a0.z; xw[3] = a0.w;
        xw[4] = a1.x; xw[5] = a1.y; xw[6] = a1.z; xw[7] = a1.w;
    }
#pragma unroll
    for (int q = 0; q < 4; ++q) {
        float4 c = *reinterpret_cast<const float4*>(xrow + l0 + q * 4);
        xw[8 + q * 4 + 0] = c.x;
        xw[8 + q * 4 + 1] = c.y;
        xw[8 + q * 4 + 2] = c.z;
        xw[8 + q * 4 + 3] = c.w;
    }

    float tv[16], pv[16];
    float gtt = 0.f, gtp = 0.f, gpp = 0.f;
#pragma unroll
    for (int j = 0; j < 16; ++j) {
        const int l = l0 + j;
        float4 wa = *reinterpret_cast<const float4*>(wrow + (size_t)l * 8);
        float4 wb = *reinterpret_cast<const float4*>(wrow + (size_t)l * 8 + 4);
        float wk[8] = {wa.x, wa.y, wa.z, wa.w, wb.x, wb.y, wb.z, wb.w};
        float t = 0.f, p = 0.f;
#pragma unroll
        for (int k = 0; k < 8; ++k) {
            float xv = xw[8 + j - k];
            t = fmaf(xv, wk[k], t);
            p = fmaf(xv, kk[k], p);
        }
        tv[j] = t;
        pv[j] = p;
        gtt = fmaf(t, t, gtt);
        gtp = fmaf(t, p, gtp);
        gpp = fmaf(p, p, gpp);
    }

    // Reduce 3 Gram scalars across the block: wave butterfly + 4-wave LDS combine.
#pragma unroll
    for (int off = 32; off > 0; off >>= 1) {
        gtt += __shfl_down(gtt, off);
        gtp += __shfl_down(gtp, off);
        gpp += __shfl_down(gpp, off);
    }
    __shared__ float red[3][4];
    const int wave = tid >> 6;
    if ((tid & 63) == 0) {
        red[0][wave] = gtt;
        red[1][wave] = gtp;
        red[2][wave] = gpp;
    }
    __syncthreads();
    const float Gtt = red[0][0] + red[0][1] + red[0][2] + red[0][3];
    const float Gtp = red[1][0] + red[1][1] + red[1][2] + red[1][3];
    const float Gpp = red[2][0] + red[2][1] + red[2][2] + red[2][3];

    // Row-softmax of [[Gtt,Gtp],[Gtp,Gpp]] (computed redundantly per thread).
    const float m0 = fmaxf(Gtt, Gtp);
    const float e00 = __expf(Gtt - m0), e01 = __expf(Gtp - m0);
    const float r0 = 1.f / (e00 + e01);
    const float m1 = fmaxf(Gtp, Gpp);
    const float e10 = __expf(Gtp - m1), e11 = __expf(Gpp - m1);
    const float r1 = 1.f / (e10 + e11);
    const float ct = 0.5f * (e00 * r0 + e10 * r1);
    const float cp = 0.5f * (e01 * r0 + e11 * r1);

#pragma unroll
    for (int q = 0; q < 4; ++q) {
        float4 o;
        o.x = fmaf(ct, tv[q * 4 + 0], cp * pv[q * 4 + 0]);
        o.y = fmaf(ct, tv[q * 4 + 1], cp * pv[q * 4 + 1]);
        o.z = fmaf(ct, tv[q * 4 + 2], cp * pv[q * 4 + 2]);
        o.w = fmaf(ct, tv[q * 4 + 3], cp * pv[q * 4 + 3]);
        *reinterpret_cast<float4*>(orow + l0 + q * 4) = o;
    }
}

extern "C" void kernel_launch(void* const* d_in, const int* in_sizes, int n_in,
                              void* d_out, int out_size, void* d_ws, size_t ws_size,
                              hipStream_t stream) {
    const float* x   = (const float*)d_in[0];   // (8, 256, 4096)
    const float* dt  = (const float*)d_in[1];   // (8, 4096)
    const float* ker = (const float*)d_in[2];   // (1, 1, 8)
    float* out = (float*)d_out;                 // (8, 256, 4096)

    const int B = 8, C = 256, L = 4096;
    float* w = (float*)d_ws;                    // (B, L, 8) f32 = 1 MiB scratch

    wtime_kernel<<<(B * L) / 256, 256, 0, stream>>>(dt, w, B, L);
    main_kernel<<<B * C, 256, 0, stream>>>(x, w, ker, out, C, L);
}

// Round 5
// 99.630 us; speedup vs baseline: 1.2239x; 1.2239x over previous
//
#include <hip/hip_runtime.h>

#define BIG 1e20f

// Kernel A: per-(b,l) 8-tap softmax weights, PLANAR layout w[b][k][l] = (B, 8, L).
// Planar makes the main kernel's w-reads contiguous along l (coalesced).
__global__ __launch_bounds__(256) void wtime_kernel(const float* __restrict__ dt,
                                                    float* __restrict__ w,
                                                    int B, int L) {
    int idx = blockIdx.x * 256 + threadIdx.x;
    int b = idx >> 12;           // L = 4096
    int l = idx & (L - 1);
    const float* dtb = dt + (size_t)b * L;
    float dtl = dtb[l];

    float v[8];
#pragma unroll
    for (int k = 0; k < 8; ++k) {
        // reference: where(l < k, BIG, dt[l-k]) - dt[l]; in fp32 BIG - dtl == BIG
        v[k] = (l < k) ? (BIG - dtl) : (dtb[l - k] - dtl);
    }
    float m = v[0];
#pragma unroll
    for (int k = 1; k < 8; ++k) m = fmaxf(m, v[k]);
    float s = 0.f;
#pragma unroll
    for (int k = 0; k < 8; ++k) { v[k] = __expf(v[k] - m); s += v[k]; }
    float inv = 1.f / s;

#pragma unroll
    for (int k = 0; k < 8; ++k)
        w[((size_t)b * 8 + k) * L + l] = v[k] * inv;   // lane-stride 4B: coalesced
}

// Kernel B: one block per (b,c) row (2048 blocks x 256 threads).
// Each thread owns 16 l-values as 4 groups of 4 CONSECUTIVE l, groups strided by 1024.
// All global loads/stores have 16B lane stride -> fully coalesced.
__global__ __launch_bounds__(256) void main_kernel(const float* __restrict__ x,
                                                   const float* __restrict__ w,
                                                   const float* __restrict__ ker,
                                                   float* __restrict__ out,
                                                   int C, int L) {
    const int bc  = blockIdx.x;       // b*C + c
    const int b   = bc >> 8;          // C = 256
    const int tid = threadIdx.x;

    const float* xrow = x + (size_t)bc * L;
    const float* wb   = w + (size_t)b * 8 * L;   // planar (8, L)
    float*       orow = out + (size_t)bc * L;

    float kk[8];
#pragma unroll
    for (int k = 0; k < 8; ++k) kk[k] = ker[k];

    float tv[16], pv[16];
    float gtt = 0.f, gtp = 0.f, gpp = 0.f;

#pragma unroll
    for (int g = 0; g < 4; ++g) {
        const int l0 = g * 1024 + tid * 4;

        // x window regs: xr[i] = x[l0 - 8 + i], i in [0,12). Window used: x[l0-7 .. l0+3].
        float xr[12];
        if (g == 0 && tid < 2) {
            // l0 == 0 or 4: positions < 0 are masked to zero (causal window).
            if (tid == 0) {
#pragma unroll
                for (int i = 0; i < 8; ++i) xr[i] = 0.f;
            } else {
#pragma unroll
                for (int i = 0; i < 4; ++i) xr[i] = 0.f;
                float4 c4 = *reinterpret_cast<const float4*>(xrow + 0);  // l0-4 == 0
                xr[4] = c4.x; xr[5] = c4.y; xr[6] = c4.z; xr[7] = c4.w;
            }
        } else {
            float4 a4 = *reinterpret_cast<const float4*>(xrow + l0 - 8);
            float4 c4 = *reinterpret_cast<const float4*>(xrow + l0 - 4);
            xr[0] = a4.x; xr[1] = a4.y; xr[2] = a4.z; xr[3] = a4.w;
            xr[4] = c4.x; xr[5] = c4.y; xr[6] = c4.z; xr[7] = c4.w;
        }
        {
            float4 d4 = *reinterpret_cast<const float4*>(xrow + l0);
            xr[8] = d4.x; xr[9] = d4.y; xr[10] = d4.z; xr[11] = d4.w;
        }

        float t[4] = {0.f, 0.f, 0.f, 0.f};
        float p[4] = {0.f, 0.f, 0.f, 0.f};
#pragma unroll
        for (int k = 0; k < 8; ++k) {
            float4 wv = *reinterpret_cast<const float4*>(wb + (size_t)k * L + l0);
            float wk4[4] = {wv.x, wv.y, wv.z, wv.w};
#pragma unroll
            for (int j = 0; j < 4; ++j) {
                float xv = xr[8 + j - k];          // static index after unroll
                t[j] = fmaf(xv, wk4[j], t[j]);
                p[j] = fmaf(xv, kk[k], p[j]);
            }
        }
#pragma unroll
        for (int j = 0; j < 4; ++j) {
            tv[g * 4 + j] = t[j];
            pv[g * 4 + j] = p[j];
            gtt = fmaf(t[j], t[j], gtt);
            gtp = fmaf(t[j], p[j], gtp);
            gpp = fmaf(p[j], p[j], gpp);
        }
    }

    // Block-reduce the 3 Gram scalars: wave butterfly + 4-wave LDS combine.
#pragma unroll
    for (int off = 32; off > 0; off >>= 1) {
        gtt += __shfl_down(gtt, off);
        gtp += __shfl_down(gtp, off);
        gpp += __shfl_down(gpp, off);
    }
    __shared__ float red[3][4];
    const int wave = tid >> 6;
    if ((tid & 63) == 0) {
        red[0][wave] = gtt;
        red[1][wave] = gtp;
        red[2][wave] = gpp;
    }
    __syncthreads();
    const float Gtt = red[0][0] + red[0][1] + red[0][2] + red[0][3];
    const float Gtp = red[1][0] + red[1][1] + red[1][2] + red[1][3];
    const float Gpp = red[2][0] + red[2][1] + red[2][2] + red[2][3];

    // Row-softmax of [[Gtt,Gtp],[Gtp,Gpp]]; out = ct*t + cp*p.
    const float m0 = fmaxf(Gtt, Gtp);
    const float e00 = __expf(Gtt - m0), e01 = __expf(Gtp - m0);
    const float r0 = 1.f / (e00 + e01);
    const float m1 = fmaxf(Gtp, Gpp);
    const float e10 = __expf(Gtp - m1), e11 = __expf(Gpp - m1);
    const float r1 = 1.f / (e10 + e11);
    const float ct = 0.5f * (e00 * r0 + e10 * r1);
    const float cp = 0.5f * (e01 * r0 + e11 * r1);

#pragma unroll
    for (int g = 0; g < 4; ++g) {
        const int l0 = g * 1024 + tid * 4;
        float4 o;
        o.x = fmaf(ct, tv[g * 4 + 0], cp * pv[g * 4 + 0]);
        o.y = fmaf(ct, tv[g * 4 + 1], cp * pv[g * 4 + 1]);
        o.z = fmaf(ct, tv[g * 4 + 2], cp * pv[g * 4 + 2]);
        o.w = fmaf(ct, tv[g * 4 + 3], cp * pv[g * 4 + 3]);
        *reinterpret_cast<float4*>(orow + l0) = o;
    }
}

extern "C" void kernel_launch(void* const* d_in, const int* in_sizes, int n_in,
                              void* d_out, int out_size, void* d_ws, size_t ws_size,
                              hipStream_t stream) {
    const float* x   = (const float*)d_in[0];   // (8, 256, 4096)
    const float* dt  = (const float*)d_in[1];   // (8, 4096)
    const float* ker = (const float*)d_in[2];   // (1, 1, 8)
    float* out = (float*)d_out;                 // (8, 256, 4096)

    const int B = 8, C = 256, L = 4096;
    float* w = (float*)d_ws;                    // planar (B, 8, L) f32 = 1 MiB scratch

    wtime_kernel<<<(B * L) / 256, 256, 0, stream>>>(dt, w, B, L);
    main_kernel<<<B * C, 256, 0, stream>>>(x, w, ker, out, C, L);
}

// Round 7
// 96.034 us; speedup vs baseline: 1.2697x; 1.0374x over previous
//
#include <hip/hip_runtime.h>

#define BIG 1e20f

// Kernel A: per-(b,l) 8-tap softmax weights, PLANAR layout w[b][k][l] = (B, 8, L).
__global__ __launch_bounds__(256) void wtime_kernel(const float* __restrict__ dt,
                                                    float* __restrict__ w,
                                                    int B, int L) {
    int idx = blockIdx.x * 256 + threadIdx.x;
    int b = idx >> 12;           // L = 4096
    int l = idx & (L - 1);
    const float* dtb = dt + (size_t)b * L;
    float dtl = dtb[l];

    float v[8];
#pragma unroll
    for (int k = 0; k < 8; ++k) {
        // reference: where(l < k, BIG, dt[l-k]) - dt[l]; in fp32 BIG - dtl == BIG
        v[k] = (l < k) ? (BIG - dtl) : (dtb[l - k] - dtl);
    }
    float m = v[0];
#pragma unroll
    for (int k = 1; k < 8; ++k) m = fmaxf(m, v[k]);
    float s = 0.f;
#pragma unroll
    for (int k = 0; k < 8; ++k) { v[k] = __expf(v[k] - m); s += v[k]; }
    float inv = 1.f / s;

#pragma unroll
    for (int k = 0; k < 8; ++k)
        w[((size_t)b * 8 + k) * L + l] = v[k] * inv;   // lane-stride 4B: coalesced
}

// Kernel B: one block per (b, channel-PAIR) -> 1024 blocks x 256 threads.
// Each thread owns 16 l (4 groups of 4 consecutive l, groups strided by 1024)
// for TWO channels that share the same w-tile: the 8 w-loads per group now
// feed 8 outputs instead of 4 (VMEM/elem 3.0 -> 2.0; w L2 traffic halved).
__global__ __launch_bounds__(256) void main_kernel(const float* __restrict__ x,
                                                   const float* __restrict__ w,
                                                   const float* __restrict__ ker,
                                                   float* __restrict__ out,
                                                   int C, int L) {
    const int pair = blockIdx.x;        // b * 128 + c/2
    const int b    = pair >> 7;         // C/2 = 128 pairs per batch
    const int c0   = (pair & 127) << 1;
    const int tid  = threadIdx.x;

    const float* x0 = x + ((size_t)b * C + c0) * L;
    const float* x1 = x0 + L;
    const float* wb = w + (size_t)b * 8 * L;    // planar (8, L)
    float*       o0 = out + ((size_t)b * C + c0) * L;
    float*       o1 = o0 + L;

    float kk[8];
#pragma unroll
    for (int k = 0; k < 8; ++k) kk[k] = ker[k];

    float tv0[16], pv0[16], tv1[16], pv1[16];
    float gtt0 = 0.f, gtp0 = 0.f, gpp0 = 0.f;
    float gtt1 = 0.f, gtp1 = 0.f, gpp1 = 0.f;

#pragma unroll
    for (int g = 0; g < 4; ++g) {
        const int l0 = g * 1024 + tid * 4;

        // x windows: xr[i] = x[l0 - 8 + i], i in [0,12), per channel.
        float xr0[12], xr1[12];
        if (g == 0 && tid < 2) {
            if (tid == 0) {
#pragma unroll
                for (int i = 0; i < 8; ++i) { xr0[i] = 0.f; xr1[i] = 0.f; }
            } else {
#pragma unroll
                for (int i = 0; i < 4; ++i) { xr0[i] = 0.f; xr1[i] = 0.f; }
                float4 a = *reinterpret_cast<const float4*>(x0 + 0);
                float4 b4 = *reinterpret_cast<const float4*>(x1 + 0);
                xr0[4] = a.x;  xr0[5] = a.y;  xr0[6] = a.z;  xr0[7] = a.w;
                xr1[4] = b4.x; xr1[5] = b4.y; xr1[6] = b4.z; xr1[7] = b4.w;
            }
        } else {
            float4 a0 = *reinterpret_cast<const float4*>(x0 + l0 - 8);
            float4 c4 = *reinterpret_cast<const float4*>(x0 + l0 - 4);
            xr0[0] = a0.x; xr0[1] = a0.y; xr0[2] = a0.z; xr0[3] = a0.w;
            xr0[4] = c4.x; xr0[5] = c4.y; xr0[6] = c4.z; xr0[7] = c4.w;
            float4 a1 = *reinterpret_cast<const float4*>(x1 + l0 - 8);
            float4 c1 = *reinterpret_cast<const float4*>(x1 + l0 - 4);
            xr1[0] = a1.x; xr1[1] = a1.y; xr1[2] = a1.z; xr1[3] = a1.w;
            xr1[4] = c1.x; xr1[5] = c1.y; xr1[6] = c1.z; xr1[7] = c1.w;
        }
        {
            float4 d0 = *reinterpret_cast<const float4*>(x0 + l0);
            xr0[8] = d0.x; xr0[9] = d0.y; xr0[10] = d0.z; xr0[11] = d0.w;
            float4 d1 = *reinterpret_cast<const float4*>(x1 + l0);
            xr1[8] = d1.x; xr1[9] = d1.y; xr1[10] = d1.z; xr1[11] = d1.w;
        }

        float t0[4] = {0.f, 0.f, 0.f, 0.f}, p0[4] = {0.f, 0.f, 0.f, 0.f};
        float t1[4] = {0.f, 0.f, 0.f, 0.f}, p1[4] = {0.f, 0.f, 0.f, 0.f};
#pragma unroll
        for (int k = 0; k < 8; ++k) {
            float4 wv = *reinterpret_cast<const float4*>(wb + (size_t)k * L + l0);
            float wk4[4] = {wv.x, wv.y, wv.z, wv.w};
#pragma unroll
            for (int j = 0; j < 4; ++j) {
                float xv0 = xr0[8 + j - k];        // static index after unroll
                float xv1 = xr1[8 + j - k];
                t0[j] = fmaf(xv0, wk4[j], t0[j]);
                p0[j] = fmaf(xv0, kk[k], p0[j]);
                t1[j] = fmaf(xv1, wk4[j], t1[j]);
                p1[j] = fmaf(xv1, kk[k], p1[j]);
            }
        }
#pragma unroll
        for (int j = 0; j < 4; ++j) {
            tv0[g * 4 + j] = t0[j];  pv0[g * 4 + j] = p0[j];
            tv1[g * 4 + j] = t1[j];  pv1[g * 4 + j] = p1[j];
            gtt0 = fmaf(t0[j], t0[j], gtt0);
            gtp0 = fmaf(t0[j], p0[j], gtp0);
            gpp0 = fmaf(p0[j], p0[j], gpp0);
            gtt1 = fmaf(t1[j], t1[j], gtt1);
            gtp1 = fmaf(t1[j], p1[j], gtp1);
            gpp1 = fmaf(p1[j], p1[j], gpp1);
        }
    }

    // Block-reduce 6 Gram scalars: wave butterfly + 4-wave LDS combine.
    float gr[6] = {gtt0, gtp0, gpp0, gtt1, gtp1, gpp1};
#pragma unroll
    for (int off = 32; off > 0; off >>= 1) {
#pragma unroll
        for (int i = 0; i < 6; ++i) gr[i] += __shfl_down(gr[i], off);
    }
    __shared__ float red[6][4];
    const int wave = tid >> 6;
    if ((tid & 63) == 0) {
#pragma unroll
        for (int i = 0; i < 6; ++i) red[i][wave] = gr[i];
    }
    __syncthreads();
    float G[6];
#pragma unroll
    for (int i = 0; i < 6; ++i) G[i] = red[i][0] + red[i][1] + red[i][2] + red[i][3];

    // Per-channel row-softmax of [[Gtt,Gtp],[Gtp,Gpp]]; out = ct*t + cp*p.
    float ct[2], cp[2];
#pragma unroll
    for (int ch = 0; ch < 2; ++ch) {
        const float Gtt = G[ch * 3 + 0], Gtp = G[ch * 3 + 1], Gpp = G[ch * 3 + 2];
        const float m0 = fmaxf(Gtt, Gtp);
        const float e00 = __expf(Gtt - m0), e01 = __expf(Gtp - m0);
        const float r0 = 1.f / (e00 + e01);
        const float m1 = fmaxf(Gtp, Gpp);
        const float e10 = __expf(Gtp - m1), e11 = __expf(Gpp - m1);
        const float r1 = 1.f / (e10 + e11);
        ct[ch] = 0.5f * (e00 * r0 + e10 * r1);
        cp[ch] = 0.5f * (e01 * r0 + e11 * r1);
    }

#pragma unroll
    for (int g = 0; g < 4; ++g) {
        const int l0 = g * 1024 + tid * 4;
        float4 oa, ob;
        oa.x = fmaf(ct[0], tv0[g * 4 + 0], cp[0] * pv0[g * 4 + 0]);
        oa.y = fmaf(ct[0], tv0[g * 4 + 1], cp[0] * pv0[g * 4 + 1]);
        oa.z = fmaf(ct[0], tv0[g * 4 + 2], cp[0] * pv0[g * 4 + 2]);
        oa.w = fmaf(ct[0], tv0[g * 4 + 3], cp[0] * pv0[g * 4 + 3]);
        *reinterpret_cast<float4*>(o0 + l0) = oa;
        ob.x = fmaf(ct[1], tv1[g * 4 + 0], cp[1] * pv1[g * 4 + 0]);
        ob.y = fmaf(ct[1], tv1[g * 4 + 1], cp[1] * pv1[g * 4 + 1]);
        ob.z = fmaf(ct[1], tv1[g * 4 + 2], cp[1] * pv1[g * 4 + 2]);
        ob.w = fmaf(ct[1], tv1[g * 4 + 3], cp[1] * pv1[g * 4 + 3]);
        *reinterpret_cast<float4*>(o1 + l0) = ob;
    }
}

extern "C" void kernel_launch(void* const* d_in, const int* in_sizes, int n_in,
                              void* d_out, int out_size, void* d_ws, size_t ws_size,
                              hipStream_t stream) {
    const float* x   = (const float*)d_in[0];   // (8, 256, 4096)
    const float* dt  = (const float*)d_in[1];   // (8, 4096)
    const float* ker = (const float*)d_in[2];   // (1, 1, 8)
    float* out = (float*)d_out;                 // (8, 256, 4096)

    const int B = 8, C = 256, L = 4096;
    float* w = (float*)d_ws;                    // planar (B, 8, L) f32 = 1 MiB scratch

    wtime_kernel<<<(B * L) / 256, 256, 0, stream>>>(dt, w, B, L);
    main_kernel<<<(B * C) / 2, 256, 0, stream>>>(x, w, ker, out, C, L);
}

// Round 8
// 94.517 us; speedup vs baseline: 1.2901x; 1.0161x over previous
//
#include <hip/hip_runtime.h>

#define BIG 1e20f

// Single fused kernel: one block per (b, channel-PAIR) -> 1024 blocks x 512 thr.
// Each thread owns 8 l (2 groups of 4 consecutive l, groups strided by 2048)
// for TWO channels sharing the inline-computed softmax weights.
// w_time is computed in-register from delta_time: OOB dt-window slots = BIG
// reproduce the reference's sentinel semantics exactly (fp32 1e20-x == 1e20);
// OOB x-window slots = 0 reproduce the causal mask.
__global__ __launch_bounds__(512) void fused_kernel(const float* __restrict__ x,
                                                    const float* __restrict__ dt,
                                                    const float* __restrict__ ker,
                                                    float* __restrict__ out,
                                                    int C, int L) {
    const int pair = blockIdx.x;        // b * 128 + c/2
    const int b    = pair >> 7;         // C/2 = 128 pairs per batch
    const int c0   = (pair & 127) << 1;
    const int tid  = threadIdx.x;

    const float* x0  = x + ((size_t)b * C + c0) * L;
    const float* x1  = x0 + L;
    const float* dtb = dt + (size_t)b * L;
    float*       o0  = out + ((size_t)b * C + c0) * L;
    float*       o1  = o0 + L;

    float kk[8];
#pragma unroll
    for (int k = 0; k < 8; ++k) kk[k] = ker[k];

    float tv0[8], pv0[8], tv1[8], pv1[8];
    float gr[6] = {0.f, 0.f, 0.f, 0.f, 0.f, 0.f};   // tt0,tp0,pp0,tt1,tp1,pp1

#pragma unroll
    for (int g = 0; g < 2; ++g) {
        const int l0 = g * 2048 + tid * 4;

        // Windows: slot i holds position l0 - 8 + i, i in [0,12).
        float xr0[12], xr1[12], dtr[12];
        if (g == 0 && tid < 2) {
            if (tid == 0) {
#pragma unroll
                for (int i = 0; i < 8; ++i) { xr0[i] = 0.f; xr1[i] = 0.f; dtr[i] = BIG; }
            } else {
#pragma unroll
                for (int i = 0; i < 4; ++i) { xr0[i] = 0.f; xr1[i] = 0.f; dtr[i] = BIG; }
                float4 a = *reinterpret_cast<const float4*>(x0 + 0);
                float4 bb = *reinterpret_cast<const float4*>(x1 + 0);
                float4 d = *reinterpret_cast<const float4*>(dtb + 0);
                xr0[4] = a.x;  xr0[5] = a.y;  xr0[6] = a.z;  xr0[7] = a.w;
                xr1[4] = bb.x; xr1[5] = bb.y; xr1[6] = bb.z; xr1[7] = bb.w;
                dtr[4] = d.x;  dtr[5] = d.y;  dtr[6] = d.z;  dtr[7] = d.w;
            }
        } else {
            float4 a0 = *reinterpret_cast<const float4*>(x0 + l0 - 8);
            float4 c4 = *reinterpret_cast<const float4*>(x0 + l0 - 4);
            xr0[0] = a0.x; xr0[1] = a0.y; xr0[2] = a0.z; xr0[3] = a0.w;
            xr0[4] = c4.x; xr0[5] = c4.y; xr0[6] = c4.z; xr0[7] = c4.w;
            float4 a1 = *reinterpret_cast<const float4*>(x1 + l0 - 8);
            float4 c1 = *reinterpret_cast<const float4*>(x1 + l0 - 4);
            xr1[0] = a1.x; xr1[1] = a1.y; xr1[2] = a1.z; xr1[3] = a1.w;
            xr1[4] = c1.x; xr1[5] = c1.y; xr1[6] = c1.z; xr1[7] = c1.w;
            float4 d0 = *reinterpret_cast<const float4*>(dtb + l0 - 8);
            float4 d1 = *reinterpret_cast<const float4*>(dtb + l0 - 4);
            dtr[0] = d0.x; dtr[1] = d0.y; dtr[2] = d0.z; dtr[3] = d0.w;
            dtr[4] = d1.x; dtr[5] = d1.y; dtr[6] = d1.z; dtr[7] = d1.w;
        }
        {
            float4 e0 = *reinterpret_cast<const float4*>(x0 + l0);
            xr0[8] = e0.x; xr0[9] = e0.y; xr0[10] = e0.z; xr0[11] = e0.w;
            float4 e1 = *reinterpret_cast<const float4*>(x1 + l0);
            xr1[8] = e1.x; xr1[9] = e1.y; xr1[10] = e1.z; xr1[11] = e1.w;
            float4 ed = *reinterpret_cast<const float4*>(dtb + l0);
            dtr[8] = ed.x; dtr[9] = ed.y; dtr[10] = ed.z; dtr[11] = ed.w;
        }

#pragma unroll
        for (int j = 0; j < 4; ++j) {
            // Inline 8-tap softmax for this l (identical math to reference).
            const float dtl = dtr[8 + j];
            float v[8];
#pragma unroll
            for (int k = 0; k < 8; ++k) v[k] = dtr[8 + j - k] - dtl;
            float m = v[0];
#pragma unroll
            for (int k = 1; k < 8; ++k) m = fmaxf(m, v[k]);
            float s = 0.f;
#pragma unroll
            for (int k = 0; k < 8; ++k) { v[k] = __expf(v[k] - m); s += v[k]; }
            const float inv = 1.f / s;

            float t0 = 0.f, p0 = 0.f, t1 = 0.f, p1 = 0.f;
#pragma unroll
            for (int k = 0; k < 8; ++k) {
                const float wk  = v[k] * inv;
                const float xa  = xr0[8 + j - k];
                const float xb  = xr1[8 + j - k];
                t0 = fmaf(xa, wk, t0);
                p0 = fmaf(xa, kk[k], p0);
                t1 = fmaf(xb, wk, t1);
                p1 = fmaf(xb, kk[k], p1);
            }
            tv0[g * 4 + j] = t0;  pv0[g * 4 + j] = p0;
            tv1[g * 4 + j] = t1;  pv1[g * 4 + j] = p1;
            gr[0] = fmaf(t0, t0, gr[0]);
            gr[1] = fmaf(t0, p0, gr[1]);
            gr[2] = fmaf(p0, p0, gr[2]);
            gr[3] = fmaf(t1, t1, gr[3]);
            gr[4] = fmaf(t1, p1, gr[4]);
            gr[5] = fmaf(p1, p1, gr[5]);
        }
    }

    // Block-reduce 6 Gram scalars: wave butterfly + 8-wave LDS combine.
#pragma unroll
    for (int off = 32; off > 0; off >>= 1) {
#pragma unroll
        for (int i = 0; i < 6; ++i) gr[i] += __shfl_down(gr[i], off);
    }
    __shared__ float red[6][8];
    const int wave = tid >> 6;
    if ((tid & 63) == 0) {
#pragma unroll
        for (int i = 0; i < 6; ++i) red[i][wave] = gr[i];
    }
    __syncthreads();
    float G[6];
#pragma unroll
    for (int i = 0; i < 6; ++i) {
        float acc = 0.f;
#pragma unroll
        for (int wv = 0; wv < 8; ++wv) acc += red[i][wv];
        G[i] = acc;
    }

    // Per-channel row-softmax of [[Gtt,Gtp],[Gtp,Gpp]]; out = ct*t + cp*p.
    float ct[2], cp[2];
#pragma unroll
    for (int ch = 0; ch < 2; ++ch) {
        const float Gtt = G[ch * 3 + 0], Gtp = G[ch * 3 + 1], Gpp = G[ch * 3 + 2];
        const float m0 = fmaxf(Gtt, Gtp);
        const float e00 = __expf(Gtt - m0), e01 = __expf(Gtp - m0);
        const float r0 = 1.f / (e00 + e01);
        const float m1 = fmaxf(Gtp, Gpp);
        const float e10 = __expf(Gtp - m1), e11 = __expf(Gpp - m1);
        const float r1 = 1.f / (e10 + e11);
        ct[ch] = 0.5f * (e00 * r0 + e10 * r1);
        cp[ch] = 0.5f * (e01 * r0 + e11 * r1);
    }

#pragma unroll
    for (int g = 0; g < 2; ++g) {
        const int l0 = g * 2048 + tid * 4;
        float4 oa, ob;
        oa.x = fmaf(ct[0], tv0[g * 4 + 0], cp[0] * pv0[g * 4 + 0]);
        oa.y = fmaf(ct[0], tv0[g * 4 + 1], cp[0] * pv0[g * 4 + 1]);
        oa.z = fmaf(ct[0], tv0[g * 4 + 2], cp[0] * pv0[g * 4 + 2]);
        oa.w = fmaf(ct[0], tv0[g * 4 + 3], cp[0] * pv0[g * 4 + 3]);
        *reinterpret_cast<float4*>(o0 + l0) = oa;
        ob.x = fmaf(ct[1], tv1[g * 4 + 0], cp[1] * pv1[g * 4 + 0]);
        ob.y = fmaf(ct[1], tv1[g * 4 + 1], cp[1] * pv1[g * 4 + 1]);
        ob.z = fmaf(ct[1], tv1[g * 4 + 2], cp[1] * pv1[g * 4 + 2]);
        ob.w = fmaf(ct[1], tv1[g * 4 + 3], cp[1] * pv1[g * 4 + 3]);
        *reinterpret_cast<float4*>(o1 + l0) = ob;
    }
}

extern "C" void kernel_launch(void* const* d_in, const int* in_sizes, int n_in,
                              void* d_out, int out_size, void* d_ws, size_t ws_size,
                              hipStream_t stream) {
    const float* x   = (const float*)d_in[0];   // (8, 256, 4096)
    const float* dt  = (const float*)d_in[1];   // (8, 4096)
    const float* ker = (const float*)d_in[2];   // (1, 1, 8)
    float* out = (float*)d_out;                 // (8, 256, 4096)

    const int B = 8, C = 256, L = 4096;
    fused_kernel<<<(B * C) / 2, 512, 0, stream>>>(x, dt, ker, out, C, L);
}